// Round 6
// baseline (176.550 us; speedup 1.0000x reference)
//
#include <hip/hip_runtime.h>
#include <math.h>

// Problem constants (B=32, S=512, H=768)
#define Hh   768
#define Ss   512
#define Bb   32
#define NTOK (Bb * Ss)          // 16384

// ---------------- Threefry-2x32, key = (0, 42), partitionable fold ----------
// ctr = (0, i); output = x0 ^ x1. Core verified vs Random123 known-answer.
__device__ __forceinline__ void tfr(unsigned &x0, unsigned &x1, int r) {
  x0 += x1;
  x1 = (x1 << r) | (x1 >> (32 - r));   // -> v_alignbit_b32
  x1 ^= x0;
}

__device__ __forceinline__ unsigned tf_bits_0_42(unsigned ctr) {
  const unsigned ks1 = 42u, ks2 = 0x1BD11BF0u; // 0^42^0x1BD11BDA
  unsigned x0 = 0u, x1 = ctr + ks1;
  tfr(x0,x1,13); tfr(x0,x1,15); tfr(x0,x1,26); tfr(x0,x1,6);
  x0 += ks1; x1 += ks2 + 1u;
  tfr(x0,x1,17); tfr(x0,x1,29); tfr(x0,x1,16); tfr(x0,x1,24);
  x0 += ks2; x1 += 2u;
  tfr(x0,x1,13); tfr(x0,x1,15); tfr(x0,x1,26); tfr(x0,x1,6);
  x1 += ks1 + 3u;
  tfr(x0,x1,17); tfr(x0,x1,29); tfr(x0,x1,16); tfr(x0,x1,24);
  x0 += ks1; x1 += ks2 + 4u;
  tfr(x0,x1,13); tfr(x0,x1,15); tfr(x0,x1,26); tfr(x0,x1,6);
  x0 += ks2; x1 += 5u;
  return x0 ^ x1;
}

// bits -> u in [-0.99999994, 1) -> erfinv(u), fully branchless
__device__ __forceinline__ float erfinv_bits(unsigned bits) {
  float f = __uint_as_float((bits >> 9) | 0x3F800000u) - 1.0f; // [0,1)
  const float LO = -0.99999994f;
  float x = fmaxf(LO, fmaf(f, 2.0f, LO));
  float w = -__logf(fmaf(-x, x, 1.0f));   // = -log1p(-x^2), ~1ulp
  // central branch (w < 5)
  float wc = w - 2.5f;
  float pc = 2.81022636e-08f;
  pc = fmaf(pc, wc, 3.43273939e-07f);
  pc = fmaf(pc, wc, -3.5233877e-06f);
  pc = fmaf(pc, wc, -4.39150654e-06f);
  pc = fmaf(pc, wc, 0.00021858087f);
  pc = fmaf(pc, wc, -0.00125372503f);
  pc = fmaf(pc, wc, -0.00417768164f);
  pc = fmaf(pc, wc, 0.246640727f);
  pc = fmaf(pc, wc, 1.50140941f);
  // tail branch (w >= 5)
  float wt = __fsqrt_rn(w) - 3.0f;
  float pt = -0.000200214257f;
  pt = fmaf(pt, wt, 0.000100950558f);
  pt = fmaf(pt, wt, 0.00134934322f);
  pt = fmaf(pt, wt, -0.00367342844f);
  pt = fmaf(pt, wt, 0.00573950773f);
  pt = fmaf(pt, wt, -0.0076224613f);
  pt = fmaf(pt, wt, 0.00943887047f);
  pt = fmaf(pt, wt, 1.00167406f);
  pt = fmaf(pt, wt, 2.83297682f);
  float p = (w < 5.0f) ? pc : pt;         // v_cndmask
  return p * x;
}

// ---------------- Kernel 1: per-row stats of importance_scores --------------
// ws layout: [0..31]=rowmax, [32..63]=rowmin(inf->99), [64..95]=rowsum,
//            [128..128+16383] = per-token ssc (sigma * sqrt2 * STD)
__global__ __launch_bounds__(512) void row_stats_kernel(
    const float* __restrict__ imp, float* __restrict__ ws) {
  int b = blockIdx.x;
  int tid = threadIdx.x;
  float v = imp[b * Ss + tid];
  float vmax = v;
  float vmin = isinf(v) ? 99.0f : v;
  float vsum = v;
  for (int o = 32; o > 0; o >>= 1) {
    vmax = fmaxf(vmax, __shfl_down(vmax, o));
    vmin = fminf(vmin, __shfl_down(vmin, o));
    vsum += __shfl_down(vsum, o);
  }
  __shared__ float smax[8], smin[8], ssum[8];
  int wave = tid >> 6, lane = tid & 63;
  if (lane == 0) { smax[wave] = vmax; smin[wave] = vmin; ssum[wave] = vsum; }
  __syncthreads();
  if (tid == 0) {
    float a = smax[0], m = smin[0], c = ssum[0];
    for (int w = 1; w < 8; ++w) {
      a = fmaxf(a, smax[w]); m = fminf(m, smin[w]); c += ssum[w];
    }
    ws[b] = a; ws[32 + b] = m; ws[64 + b] = c;
  }
}

// ---------------- Kernel 1b: per-token ssc precompute -----------------------
__global__ __launch_bounds__(256) void sigma_kernel(
    const float* __restrict__ imp, float* __restrict__ ws) {
  const int t = blockIdx.x * 256 + threadIdx.x;
  const int b = t >> 9;
  const int s = t & 511;
  float total = 0.0f;
  #pragma unroll
  for (int w = 0; w < 32; ++w) total += ws[64 + w];
  const float score = imp[t];
  float sig = 0.0f;
  if (s != 0) {
    const bool fin = isfinite(score);
    const float mx = ws[b], mn = ws[32 + b];
    const float val = (total == 0.0f) ? score : (score - mn) / (mx - mn);
    sig = fin ? (1.0f - val) : 0.0f;
  }
  ws[128 + t] = sig * 0.70710677f;   // sqrt(2) * STD(=0.5) folded
}

// ---------------- Kernel 2: fused embed + LN + noise ------------------------
// 256 threads = 4 waves; each wave owns ONE token (12 elems/lane).
// No LDS, no __syncthreads — all reductions are wave-level shfl butterflies.
__global__ __launch_bounds__(256) void bert_embed_ln_noise_kernel(
    const int* __restrict__ ids, const int* __restrict__ tts,
    const float* __restrict__ wemb, const float* __restrict__ pemb,
    const float* __restrict__ temb, const float* __restrict__ gamma,
    const float* __restrict__ beta, const float* __restrict__ ws,
    float* __restrict__ out) {
  const int wv   = threadIdx.x >> 6;
  const int lane = threadIdx.x & 63;
  const int t = (blockIdx.x << 2) + wv;     // token index
  const int b = t >> 9;
  const int s = t & 511;
  (void)b;

  const int id = ids[t];
  const int tt = tts[t];
  const float4* wr = (const float4*)(wemb + (size_t)id * Hh);
  const float4* pr = (const float4*)(pemb + (size_t)s  * Hh);
  const float4* tr = (const float4*)(temb + (size_t)tt * Hh);

  float4 e[3];
  #pragma unroll
  for (int g = 0; g < 3; ++g) {
    const float4 a = wr[lane + 64 * g];
    const float4 p = pr[lane + 64 * g];
    const float4 c = tr[lane + 64 * g];
    e[g].x = a.x + p.x + c.x;
    e[g].y = a.y + p.y + c.y;
    e[g].z = a.z + p.z + c.z;
    e[g].w = a.w + p.w + c.w;
  }

  // mean (wave butterfly)
  float ps = ((e[0].x + e[0].y) + (e[0].z + e[0].w))
           + ((e[1].x + e[1].y) + (e[1].z + e[1].w))
           + ((e[2].x + e[2].y) + (e[2].z + e[2].w));
  #pragma unroll
  for (int o = 1; o < 64; o <<= 1) ps += __shfl_xor(ps, o);
  const float mu = ps * (1.0f / Hh);

  // variance (wave butterfly)
  float pvv = 0.0f;
  #pragma unroll
  for (int g = 0; g < 3; ++g) {
    e[g].x -= mu; e[g].y -= mu; e[g].z -= mu; e[g].w -= mu;
    pvv += (e[g].x * e[g].x + e[g].y * e[g].y)
         + (e[g].z * e[g].z + e[g].w * e[g].w);
  }
  #pragma unroll
  for (int o = 1; o < 64; o <<= 1) pvv += __shfl_xor(pvv, o);
  const float rstd = rsqrtf(pvv * (1.0f / Hh) + 1e-12f);
  const float ssc = ws[128 + t];

  const unsigned base = (unsigned)t * Hh + 4u * (unsigned)lane;
  float4* op = (float4*)(out + (size_t)t * Hh);

  #pragma unroll
  for (int g = 0; g < 3; ++g) {
    const float4 g4 = ((const float4*)gamma)[lane + 64 * g];
    const float4 b4 = ((const float4*)beta )[lane + 64 * g];
    const float y0 = fmaf(e[g].x * rstd, g4.x, b4.x);
    const float y1 = fmaf(e[g].y * rstd, g4.y, b4.y);
    const float y2 = fmaf(e[g].z * rstd, g4.z, b4.z);
    const float y3 = fmaf(e[g].w * rstd, g4.w, b4.w);

    const unsigned c0 = base + 256u * g;
    const float n0 = erfinv_bits(tf_bits_0_42(c0));
    const float n1 = erfinv_bits(tf_bits_0_42(c0 + 1u));
    const float n2 = erfinv_bits(tf_bits_0_42(c0 + 2u));
    const float n3 = erfinv_bits(tf_bits_0_42(c0 + 3u));

    float4 o4;
    o4.x = fmaf(n0 * ssc, y0, y0);
    o4.y = fmaf(n1 * ssc, y1, y1);
    o4.z = fmaf(n2 * ssc, y2, y2);
    o4.w = fmaf(n3 * ssc, y3, y3);
    op[lane + 64 * g] = o4;
  }
}

extern "C" void kernel_launch(void* const* d_in, const int* in_sizes, int n_in,
                              void* d_out, int out_size, void* d_ws, size_t ws_size,
                              hipStream_t stream) {
  const int*   ids   = (const int*)d_in[0];
  const int*   tts   = (const int*)d_in[1];
  const float* imp   = (const float*)d_in[2];
  const float* wemb  = (const float*)d_in[3];
  const float* pemb  = (const float*)d_in[4];
  const float* temb  = (const float*)d_in[5];
  const float* gamma = (const float*)d_in[6];
  const float* beta  = (const float*)d_in[7];
  float* out   = (float*)d_out;
  float* ws    = (float*)d_ws;

  row_stats_kernel<<<Bb, Ss, 0, stream>>>(imp, ws);
  sigma_kernel<<<NTOK / 256, 256, 0, stream>>>(imp, ws);
  bert_embed_ln_noise_kernel<<<NTOK / 4, 256, 0, stream>>>(
      ids, tts, wemb, pemb, temb, gamma, beta, ws, out);
}